// Round 3
// baseline (734.234 us; speedup 1.0000x reference)
//
#include <hip/hip_runtime.h>

// ---------------------------------------------------------------------------
// DeepProteinClassifier: x[32,1024,960] fp32, mask[32,1024] i32 ->
//   fused QKV proj (256^2 tile, counted-vmcnt pipeline) -> attention ->
//   PV gemm -> +x, LN -> masked mean pool -> MLP -> [32,10] f32
// ---------------------------------------------------------------------------

#define DEVINL __device__ __forceinline__

typedef __attribute__((ext_vector_type(8))) short bf16x8;
typedef __attribute__((ext_vector_type(4))) float f32x4;
typedef __attribute__((ext_vector_type(4))) unsigned short u16x4;

DEVINL unsigned short f2bf(float f) {
  unsigned int u = __float_as_uint(f);
  u += 0x7FFFu + ((u >> 16) & 1u);  // round-to-nearest-even
  return (unsigned short)(u >> 16);
}

DEVINL void gload_lds16(const void* g, void* l) {
  __builtin_amdgcn_global_load_lds((const __attribute__((address_space(1))) unsigned int*)g,
                                   (__attribute__((address_space(3))) unsigned int*)l,
                                   16, 0, 0);
}

#define MFMA16(a, b, c) __builtin_amdgcn_mfma_f32_16x16x32_bf16((a), (b), (c), 0, 0, 0)

// ---------------------------------------------------------------------------
// Build Wqkv [3072][1024] bf16 (rows: 0..959 Wq*s, 960..1919 Wk, 1920..2879 Wv;
// cols 960..1023 zero; rows 2880+ untouched) and biasQKV[2880] f32 (bq*s..).
// grid 2880 blocks x 256 threads.
// ---------------------------------------------------------------------------
__global__ __launch_bounds__(256) void cast_wqkv(
    const float* __restrict__ Wq, const float* __restrict__ Wk, const float* __restrict__ Wv,
    const float* __restrict__ bq, const float* __restrict__ bk, const float* __restrict__ bv,
    unsigned short* __restrict__ Wqkv, float* __restrict__ biasQ, float scaleQ) {
  const int r = blockIdx.x, t = threadIdx.x;
  const int seg = (r >= 1920) ? 2 : (r >= 960 ? 1 : 0);
  const int sr = r - seg * 960;
  const float* W = (seg == 0) ? Wq : (seg == 1) ? Wk : Wv;
  const float sc = (seg == 0) ? scaleQ : 1.0f;
  if (t < 240) {
    f32x4 v = *(const f32x4*)(W + (size_t)sr * 960 + t * 4);
    u16x4 o;
    o[0] = f2bf(v[0] * sc); o[1] = f2bf(v[1] * sc);
    o[2] = f2bf(v[2] * sc); o[3] = f2bf(v[3] * sc);
    *(u16x4*)(Wqkv + (size_t)r * 1024 + t * 4) = o;
  } else {
    u16x4 z = {};
    *(u16x4*)(Wqkv + (size_t)r * 1024 + 960 + (t - 240) * 4) = z;
  }
  if (t == 0) {
    const float* bb = (seg == 0) ? bq : (seg == 1) ? bk : bv;
    biasQ[r] = bb[sr] * sc;
  }
}

// ---------------------------------------------------------------------------
// cast x [32768][960] f32 -> xb [32768][1024] bf16 (cols 960.. zero).
// grid 8192 x 256 (4 rows/block, 64 lanes/row, 16 elems/lane).
// ---------------------------------------------------------------------------
__global__ __launch_bounds__(256) void cast_x(
    const float* __restrict__ x, unsigned short* __restrict__ xb) {
  const int row = blockIdx.x * 4 + (threadIdx.x >> 6);
  const int l = threadIdx.x & 63;
  unsigned short* o = xb + (size_t)row * 1024 + l * 16;
  if (l < 60) {
    const float* g = x + (size_t)row * 960 + l * 16;
    f32x4 v0 = *(const f32x4*)(g);
    f32x4 v1 = *(const f32x4*)(g + 4);
    f32x4 v2 = *(const f32x4*)(g + 8);
    f32x4 v3 = *(const f32x4*)(g + 12);
    bf16x8 o0, o1;
    o0[0] = (short)f2bf(v0[0]); o0[1] = (short)f2bf(v0[1]);
    o0[2] = (short)f2bf(v0[2]); o0[3] = (short)f2bf(v0[3]);
    o0[4] = (short)f2bf(v1[0]); o0[5] = (short)f2bf(v1[1]);
    o0[6] = (short)f2bf(v1[2]); o0[7] = (short)f2bf(v1[3]);
    o1[0] = (short)f2bf(v2[0]); o1[1] = (short)f2bf(v2[1]);
    o1[2] = (short)f2bf(v2[2]); o1[3] = (short)f2bf(v2[3]);
    o1[4] = (short)f2bf(v3[0]); o1[5] = (short)f2bf(v3[1]);
    o1[6] = (short)f2bf(v3[2]); o1[7] = (short)f2bf(v3[3]);
    *(bf16x8*)(o) = o0;
    *(bf16x8*)(o + 8) = o1;
  } else {
    bf16x8 z = {};
    *(bf16x8*)(o) = z;
    *(bf16x8*)(o + 8) = z;
  }
}

// ---------------------------------------------------------------------------
// 256x256-tile NT GEMM, BK=64, 8 waves (2 wr x 4 wc), 128x64 out per wave.
// lda = ldb = 1024 (K zero-padded). Double-buffered LDS (128 KB), staged via
// global_load_lds with (row&7) source-side XOR swizzle; counted-vmcnt
// pipeline: stage tile t+1, s_waitcnt vmcnt(8), raw s_barrier (never drains
// in-flight prefetch), compute tile t, raw s_barrier.
// MODE 0: f32 out (PV -> ctx).  MODE 1: fused QKV epilogue (bf16 +bias,
//   cols 0..959 -> Qb, 960..1919 -> Kb, 1920..2879 -> Vt transposed).
// XCD-bijective swizzle over flat grid (nwg % 8 == 0), m-chunked, n fastest.
// ---------------------------------------------------------------------------
template <int MODE>
__global__ __launch_bounds__(512, 2) void gemm256(
    const unsigned short* __restrict__ Ap, const unsigned short* __restrict__ Bp,
    const float* __restrict__ bias, float* __restrict__ outF,
    unsigned short* __restrict__ outQ, unsigned short* __restrict__ outK,
    unsigned short* __restrict__ outV,
    int mTiles, int nTiles, int ncols, int ldo,
    size_t aStride, size_t bStride, size_t oStride) {
  __shared__ unsigned short As[2][256 * 64];
  __shared__ unsigned short Bs[2][256 * 64];
  const int t = threadIdx.x, l = t & 63, w = t >> 6;
  const int wr = w >> 2, wc = w & 3;
  const int lq = l & 15, lh = l >> 4;

  const int nwg = (int)gridDim.x;
  const int flat = (int)blockIdx.x;
  const int swz = (flat & 7) * (nwg >> 3) + (flat >> 3);
  const int pt = mTiles * nTiles;
  const int zb = swz / pt;
  const int rm = swz - zb * pt;
  const int mi = rm / nTiles;
  const int m0 = mi * 256;
  const int n0 = (rm - mi * nTiles) * 256;

  const unsigned short* A = Ap + (size_t)zb * aStride + (size_t)m0 * 1024;
  const unsigned short* B = Bp + (size_t)zb * bStride + (size_t)n0 * 1024;

#define STAGE256(tt, bb)                                                      \
  {                                                                           \
    const int d0_ = (tt) * 64;                                                \
    _Pragma("unroll") for (int q_ = 0; q_ < 4; ++q_) {                        \
      const int r_ = q_ * 64 + (t >> 3);                                      \
      const int sg_ = (t & 7) ^ (r_ & 7);                                     \
      gload_lds16(A + (size_t)r_ * 1024 + d0_ + sg_ * 8,                      \
                  (char*)&As[(bb)][(q_ * 64 + w * 8) * 64]);                  \
      gload_lds16(B + (size_t)r_ * 1024 + d0_ + sg_ * 8,                      \
                  (char*)&Bs[(bb)][(q_ * 64 + w * 8) * 64]);                  \
    }                                                                         \
  }

  f32x4 acc[8][4] = {};
  STAGE256(0, 0);
  int buf = 0;
  for (int tt = 0; tt < 16; ++tt) {
    if (tt < 15) {
      STAGE256(tt + 1, buf ^ 1);
      asm volatile("s_waitcnt vmcnt(8)" ::: "memory");
    } else {
      asm volatile("s_waitcnt vmcnt(0)" ::: "memory");
    }
    __builtin_amdgcn_sched_barrier(0);
    __builtin_amdgcn_s_barrier();
#pragma unroll
    for (int kk = 0; kk < 2; ++kk) {
      bf16x8 aF[8], bF[4];
#pragma unroll
      for (int j = 0; j < 4; ++j) {
        const int row = wc * 64 + 16 * j + lq;
        bF[j] = *(const bf16x8*)&Bs[buf][row * 64 + (((kk << 2) | lh) ^ (row & 7)) * 8];
      }
#pragma unroll
      for (int i = 0; i < 8; ++i) {
        const int row = wr * 128 + 16 * i + lq;
        aF[i] = *(const bf16x8*)&As[buf][row * 64 + (((kk << 2) | lh) ^ (row & 7)) * 8];
      }
#pragma unroll
      for (int i = 0; i < 8; ++i)
#pragma unroll
        for (int j = 0; j < 4; ++j) acc[i][j] = MFMA16(aF[i], bF[j], acc[i][j]);
    }
    __builtin_amdgcn_s_barrier();
    buf ^= 1;
  }
#undef STAGE256

  // epilogue: C/D layout col = lane&15, row = (lane>>4)*4 + reg
  if (MODE == 0) {
#pragma unroll
    for (int j = 0; j < 4; ++j) {
      const int col = n0 + wc * 64 + 16 * j + lq;
      if (col >= ncols) continue;
#pragma unroll
      for (int i = 0; i < 8; ++i)
#pragma unroll
        for (int r = 0; r < 4; ++r) {
          const int row = m0 + wr * 128 + 16 * i + 4 * lh + r;
          outF[(size_t)zb * oStride + (size_t)row * ldo + col] = acc[i][j][r];
        }
    }
  } else {
#pragma unroll
    for (int j = 0; j < 4; ++j) {
      const int col = n0 + wc * 64 + 16 * j + lq;
      if (col >= 2880) continue;
      const int seg = (col >= 1920) ? 2 : (col >= 960 ? 1 : 0);
      const int dcol = col - seg * 960;
      const float bv = bias[col];
#pragma unroll
      for (int i = 0; i < 8; ++i)
#pragma unroll
        for (int r = 0; r < 4; ++r) {
          const int row = m0 + wr * 128 + 16 * i + 4 * lh + r;
          const unsigned short v = f2bf(acc[i][j][r] + bv);
          if (seg == 0) outQ[(size_t)row * 960 + dcol] = v;
          else if (seg == 1) outK[(size_t)row * 960 + dcol] = v;
          else outV[((size_t)(row >> 10) << 20) + ((size_t)dcol << 10) + (row & 1023)] = v;
        }
    }
  }
}

// ---------------------------------------------------------------------------
// Fused scores + masked softmax, v3 (counted-vmcnt pipeline).
// Block = 64 q-rows x full 1024 k for one b; 8 waves, wave w owns k-cols
// [128w,128w+128). K slab (1024x32) + Q slab (64x32) double-buffered in LDS.
// All 8 waves issue exactly 9 gloads per stage (Q slice duplicated pairwise,
// same src -> same dst, benign) so vmcnt(9) is wave-uniform.
// ---------------------------------------------------------------------------
__global__ __launch_bounds__(512, 2) void attn_softmax(
    const unsigned short* __restrict__ Qb, const unsigned short* __restrict__ Kb,
    const int* __restrict__ mask, unsigned short* __restrict__ P) {
  __shared__ unsigned short Ks[2][1024 * 32];
  __shared__ unsigned short Qs[2][64 * 32];
  __shared__ float red[2][8][64];
  const int t = threadIdx.x, l = t & 63, w = t >> 6;
  const int flat = blockIdx.x;
  const int b = (flat & 7) * 4 + ((flat >> 3) >> 4);
  const int q0 = ((flat >> 3) & 15) * 64;
  const int lq = l & 15, lh = l >> 4;
  const size_t kbase = (size_t)b * 1024 * 960;
  const size_t qbase = ((size_t)b * 1024 + q0) * 960;
  const int lr = l >> 2, sg0 = l & 3;  // 16 rows x 4 slots(16B) per 1KB issue

#define STAGE(kkv, bufv)                                                      \
  {                                                                           \
    const int d0_ = (kkv) * 32;                                               \
    _Pragma("unroll") for (int i_ = 0; i_ < 8; ++i_) {                        \
      const int br_ = i_ * 128 + w * 16;                                      \
      const int kr_ = br_ + lr;                                               \
      const int sg_ = sg0 ^ ((kr_ >> 1) & 3);                                 \
      gload_lds16(Kb + kbase + (size_t)kr_ * 960 + d0_ + sg_ * 8,             \
                  (char*)Ks[(bufv)] + (size_t)br_ * 64);                      \
    }                                                                         \
    {                                                                         \
      const int qw_ = w & 3;                                                  \
      const int qr_ = qw_ * 16 + lr;                                          \
      const int sg_ = sg0 ^ ((qr_ >> 1) & 3);                                 \
      gload_lds16(Qb + qbase + (size_t)qr_ * 960 + d0_ + sg_ * 8,             \
                  (char*)Qs[(bufv)] + (size_t)(qw_ * 16) * 64);               \
    }                                                                         \
  }

  f32x4 acc[4][8] = {};
  STAGE(0, 0);
  int buf = 0;
  for (int kk = 0; kk < 30; ++kk) {
    if (kk < 29) {
      STAGE(kk + 1, buf ^ 1);
      asm volatile("s_waitcnt vmcnt(9)" ::: "memory");
    } else {
      asm volatile("s_waitcnt vmcnt(0)" ::: "memory");
    }
    __builtin_amdgcn_sched_barrier(0);
    __builtin_amdgcn_s_barrier();
    bf16x8 aF[4], bF[8];
#pragma unroll
    for (int i = 0; i < 4; ++i) {
      const int qr = 16 * i + lq;
      aF[i] = *(const bf16x8*)(Qs[buf] + qr * 32 + (lh ^ ((qr >> 1) & 3)) * 8);
    }
#pragma unroll
    for (int j = 0; j < 8; ++j) {
      const int kr = 128 * w + 16 * j + lq;
      bF[j] = *(const bf16x8*)(Ks[buf] + kr * 32 + (lh ^ ((kr >> 1) & 3)) * 8);
    }
#pragma unroll
    for (int i = 0; i < 4; ++i)
#pragma unroll
      for (int j = 0; j < 8; ++j) acc[i][j] = MFMA16(aF[i], bF[j], acc[i][j]);
    __builtin_amdgcn_s_barrier();
    buf ^= 1;
  }
#undef STAGE

  // mask -> -1e9
#pragma unroll
  for (int j = 0; j < 8; ++j) {
    const int k = 128 * w + 16 * j + lq;
    if (mask[b * 1024 + k] == 0) {
#pragma unroll
      for (int i = 0; i < 4; ++i)
#pragma unroll
        for (int r = 0; r < 4; ++r) acc[i][j][r] = -1e9f;
    }
  }

  // row max
  float rmax[4][4];
#pragma unroll
  for (int i = 0; i < 4; ++i)
#pragma unroll
    for (int r = 0; r < 4; ++r) {
      float m = acc[i][0][r];
#pragma unroll
      for (int j = 1; j < 8; ++j) m = fmaxf(m, acc[i][j][r]);
      m = fmaxf(m, __shfl_xor(m, 1));
      m = fmaxf(m, __shfl_xor(m, 2));
      m = fmaxf(m, __shfl_xor(m, 4));
      m = fmaxf(m, __shfl_xor(m, 8));
      rmax[i][r] = m;
    }
  if (lq == 0) {
#pragma unroll
    for (int i = 0; i < 4; ++i)
#pragma unroll
      for (int r = 0; r < 4; ++r) red[0][w][16 * i + 4 * lh + r] = rmax[i][r];
  }
  __syncthreads();
#pragma unroll
  for (int i = 0; i < 4; ++i)
#pragma unroll
    for (int r = 0; r < 4; ++r) {
      const int rowi = 16 * i + 4 * lh + r;
      float m = red[0][0][rowi];
#pragma unroll
      for (int w2 = 1; w2 < 8; ++w2) m = fmaxf(m, red[0][w2][rowi]);
      rmax[i][r] = m;
    }

  float rsum[4][4];
#pragma unroll
  for (int i = 0; i < 4; ++i)
#pragma unroll
    for (int r = 0; r < 4; ++r) {
      float s = 0.f;
#pragma unroll
      for (int j = 0; j < 8; ++j) {
        const float e = __expf(acc[i][j][r] - rmax[i][r]);
        acc[i][j][r] = e;
        s += e;
      }
      s += __shfl_xor(s, 1); s += __shfl_xor(s, 2);
      s += __shfl_xor(s, 4); s += __shfl_xor(s, 8);
      rsum[i][r] = s;
    }
  if (lq == 0) {
#pragma unroll
    for (int i = 0; i < 4; ++i)
#pragma unroll
      for (int r = 0; r < 4; ++r) red[1][w][16 * i + 4 * lh + r] = rsum[i][r];
  }
  __syncthreads();

  const size_t pb = ((size_t)b << 20) + (size_t)q0 * 1024;
#pragma unroll
  for (int i = 0; i < 4; ++i)
#pragma unroll
    for (int r = 0; r < 4; ++r) {
      const int rowi = 16 * i + 4 * lh + r;
      float s = 0.f;
#pragma unroll
      for (int w2 = 0; w2 < 8; ++w2) s += red[1][w2][rowi];
      const float inv = 1.0f / s;
#pragma unroll
      for (int j = 0; j < 8; ++j) {
        const int col = 128 * w + 16 * j + lq;
        P[pb + (size_t)rowi * 1024 + col] = f2bf(acc[i][j][r] * inv);
      }
    }
}

// ---------------------------------------------------------------------------
// h = ctx + x; LayerNorm(h)*g+b; pooled[b,d] += y for masked rows (atomics).
// ---------------------------------------------------------------------------
__global__ __launch_bounds__(256) void ln_pool(
    const float* __restrict__ ctx, const float* __restrict__ x, const int* __restrict__ mask,
    const float* __restrict__ g, const float* __restrict__ bta, float* __restrict__ pooled) {
  const int b = blockIdx.y, chunk = blockIdx.x;
  const int w = threadIdx.x >> 6, l = threadIdx.x & 63;
  f32x4 gc[4], bc[4];
#pragma unroll
  for (int c = 0; c < 4; ++c) {
    const int i4 = c * 64 + l;
    if (i4 < 240) {
      gc[c] = *(const f32x4*)(g + i4 * 4);
      bc[c] = *(const f32x4*)(bta + i4 * 4);
    }
  }
  f32x4 accp[4] = {};
  for (int rr = 0; rr < 8; ++rr) {
    const int s = chunk * 32 + w * 8 + rr;
    if (mask[b * 1024 + s] == 0) continue;
    const size_t base = ((size_t)b * 1024 + s) * 960;
    f32x4 h[4];
    float part = 0.f;
#pragma unroll
    for (int c = 0; c < 4; ++c) {
      const int i4 = c * 64 + l;
      if (i4 < 240) {
        f32x4 cv = *(const f32x4*)(ctx + base + (size_t)i4 * 4);
        f32x4 xv = *(const f32x4*)(x + base + (size_t)i4 * 4);
        h[c] = cv + xv;
        part += h[c][0] + h[c][1] + h[c][2] + h[c][3];
      } else {
        h[c] = 0;
      }
    }
#pragma unroll
    for (int o = 1; o < 64; o <<= 1) part += __shfl_xor(part, o);
    const float mu = part * (1.0f / 960.0f);
    float p2 = 0.f;
#pragma unroll
    for (int c = 0; c < 4; ++c) {
      if (c * 64 + l < 240) {
#pragma unroll
        for (int k2 = 0; k2 < 4; ++k2) {
          const float d = h[c][k2] - mu;
          p2 += d * d;
        }
      }
    }
#pragma unroll
    for (int o = 1; o < 64; o <<= 1) p2 += __shfl_xor(p2, o);
    const float rs = rsqrtf(p2 * (1.0f / 960.0f) + 1e-5f);
#pragma unroll
    for (int c = 0; c < 4; ++c) {
      if (c * 64 + l < 240) {
#pragma unroll
        for (int k2 = 0; k2 < 4; ++k2)
          accp[c][k2] += (h[c][k2] - mu) * rs * gc[c][k2] + bc[c][k2];
      }
    }
  }
#pragma unroll
  for (int c = 0; c < 4; ++c) {
    const int i4 = c * 64 + l;
    if (i4 < 240) {
#pragma unroll
      for (int k2 = 0; k2 < 4; ++k2) atomicAdd(&pooled[b * 960 + i4 * 4 + k2], accp[c][k2]);
    }
  }
}

// ---------------------------------------------------------------------------
// pooled/count -> 960-512-256-128-10 MLP fp32. One block per batch row.
// ---------------------------------------------------------------------------
__global__ __launch_bounds__(256) void mlp_head(
    const float* __restrict__ pooled, const int* __restrict__ mask,
    const float* __restrict__ W1, const float* __restrict__ b1,
    const float* __restrict__ W2, const float* __restrict__ b2,
    const float* __restrict__ W3, const float* __restrict__ b3,
    const float* __restrict__ W4, const float* __restrict__ b4, float* __restrict__ out) {
  __shared__ float h0[960], h1[512], h2[256], h3[128];
  __shared__ float csh[4];
  const int b = blockIdx.x, t = threadIdx.x;
  int cnt = 0;
  for (int s = t; s < 1024; s += 256) cnt += (mask[b * 1024 + s] != 0) ? 1 : 0;
#pragma unroll
  for (int o = 1; o < 64; o <<= 1) cnt += __shfl_xor(cnt, o);
  if ((t & 63) == 0) csh[t >> 6] = (float)cnt;
  __syncthreads();
  const float inv = 1.0f / fmaxf(csh[0] + csh[1] + csh[2] + csh[3], 1e-9f);
  for (int d = t; d < 960; d += 256) h0[d] = pooled[b * 960 + d] * inv;
  __syncthreads();
  for (int o = t; o < 512; o += 256) {
    float a = b1[o];
    const float* wr = W1 + (size_t)o * 960;
    for (int k = 0; k < 960; k += 4) {
      f32x4 wv = *(const f32x4*)(wr + k);
      f32x4 hv = *(const f32x4*)(h0 + k);
      a += wv[0] * hv[0] + wv[1] * hv[1] + wv[2] * hv[2] + wv[3] * hv[3];
    }
    h1[o] = fmaxf(a, 0.f);
  }
  __syncthreads();
  {
    float a = b2[t];
    const float* wr = W2 + (size_t)t * 512;
    for (int k = 0; k < 512; k += 4) {
      f32x4 wv = *(const f32x4*)(wr + k);
      f32x4 hv = *(const f32x4*)(h1 + k);
      a += wv[0] * hv[0] + wv[1] * hv[1] + wv[2] * hv[2] + wv[3] * hv[3];
    }
    h2[t] = fmaxf(a, 0.f);
  }
  __syncthreads();
  if (t < 128) {
    float a = b3[t];
    const float* wr = W3 + (size_t)t * 256;
    for (int k = 0; k < 256; k += 4) {
      f32x4 wv = *(const f32x4*)(wr + k);
      f32x4 hv = *(const f32x4*)(h2 + k);
      a += wv[0] * hv[0] + wv[1] * hv[1] + wv[2] * hv[2] + wv[3] * hv[3];
    }
    h3[t] = fmaxf(a, 0.f);
  }
  __syncthreads();
  if (t < 10) {
    float a = b4[t];
    const float* wr = W4 + (size_t)t * 128;
    for (int k = 0; k < 128; ++k) a += wr[k] * h3[k];
    out[b * 10 + t] = a;
  }
}

// ---------------------------------------------------------------------------
// Workspace (bytes):
//   [0,          67108864)  xb bf16 [32768][1024]  -> later P bf16 [32][1024][1024]
//   [67108864,  130023424)  Qb bf16 [32768][960]   \ after attn: ctx f32 [32768][960]
//   [130023424, 192937984)  Kb bf16 [32768][960]   /   (exactly 125829120 B)
//   [192937984, 260046848)  Vt bf16 [32][1024][1024]
//   [260046848, 260169728)  pooled f32 [32][960]
//   [260169728, 266461184)  Wqkv bf16 [3072][1024]; biasQKV f32[2880] lives in
//                           Wqkv's unused rows (byte 266067968+)
// ---------------------------------------------------------------------------
extern "C" void kernel_launch(void* const* d_in, const int* in_sizes, int n_in,
                              void* d_out, int out_size, void* d_ws, size_t ws_size,
                              hipStream_t stream) {
  (void)in_sizes; (void)n_in; (void)out_size; (void)ws_size;
  const float* x    = (const float*)d_in[0];
  const int*   mask = (const int*)d_in[1];
  const float* Wq   = (const float*)d_in[2];
  const float* bq   = (const float*)d_in[3];
  const float* Wk   = (const float*)d_in[4];
  const float* bk   = (const float*)d_in[5];
  const float* Wv   = (const float*)d_in[6];
  const float* bv   = (const float*)d_in[7];
  const float* lng  = (const float*)d_in[8];
  const float* lnb  = (const float*)d_in[9];
  const float* W1   = (const float*)d_in[10];
  const float* b1   = (const float*)d_in[11];
  const float* W2   = (const float*)d_in[12];
  const float* b2   = (const float*)d_in[13];
  const float* W3   = (const float*)d_in[14];
  const float* b3   = (const float*)d_in[15];
  const float* W4   = (const float*)d_in[16];
  const float* b4   = (const float*)d_in[17];
  float* out = (float*)d_out;

  char* ws = (char*)d_ws;
  unsigned short* xb     = (unsigned short*)(ws);
  unsigned short* P      = (unsigned short*)(ws);
  unsigned short* Qb     = (unsigned short*)(ws + 67108864);
  unsigned short* Kb     = (unsigned short*)(ws + 130023424);
  float*          ctx    = (float*)(ws + 67108864);
  unsigned short* Vt     = (unsigned short*)(ws + 192937984);
  float*          pooled = (float*)(ws + 260046848);
  unsigned short* Wqkv   = (unsigned short*)(ws + 260169728);
  float*          biasQ  = (float*)(ws + 266067968);

  const float scaleQ = 0.0322748612183951f;  // 1/sqrt(960)

  cast_wqkv<<<2880, 256, 0, stream>>>(Wq, Wk, Wv, bq, bk, bv, Wqkv, biasQ, scaleQ);
  cast_x<<<8192, 256, 0, stream>>>(x, xb);

  // fused QKV: [32768 x 2880] = xb[32768x1024] . Wqkv^T ; writes Qb, Kb, Vt(T)
  gemm256<1><<<128 * 12, 512, 0, stream>>>(
      xb, Wqkv, biasQ, nullptr, Qb, Kb, Vt, 128, 12, 2880, 0, 0, 0, 0);

  attn_softmax<<<512, 512, 0, stream>>>(Qb, Kb, mask, P);

  // context[b] = P[b] . Vt[b]^T : M=1024, N=960(pad 1024), K=1024, f32 out
  gemm256<0><<<4 * 4 * 32, 512, 0, stream>>>(
      P, Vt, nullptr, ctx, nullptr, nullptr, nullptr, 4, 4, 960, 960,
      (size_t)1048576, (size_t)1048576, (size_t)983040);

  hipMemsetAsync(pooled, 0, 32 * 960 * 4, stream);
  ln_pool<<<dim3(32, 32), 256, 0, stream>>>(ctx, x, mask, lng, lnb, pooled);
  mlp_head<<<32, 256, 0, stream>>>(pooled, mask, W1, b1, W2, b2, W3, b3, W4, b4, out);
}